// Round 9
// baseline (1172.897 us; speedup 1.0000x reference)
//
#include <hip/hip_runtime.h>
#include <math.h>

// Multi_Adaptation_Module on MI355X. Round 9 = Round 8 (passing) + XCD-aware
// block swizzle in mm_k: 1D grid, id = xcd + 8*(x + nx*g) so all nx N-blocks
// of one (M-tile,batch) run consecutively on ONE XCD -> shared A-tile hits
// that XCD's private L2 instead of being re-fetched from HBM per N-block.
// (Round-8 counters: conv GEMMs at FETCH 82MB = A re-fetched x4-8; ideal 17MB.)
// Requires ny*nz % 8 == 0 for bijectivity -- true for every launch here.

#define B_ 4
#define C_ 512
#define N_ 4096
#define TM 128
#define TN 128

typedef unsigned short u16;
typedef __attribute__((ext_vector_type(8))) short s8v;   // 8 bf16 (4 VGPR)
typedef __attribute__((ext_vector_type(4))) float f4v;

__device__ __forceinline__ u16 f2bf(float x) {
  unsigned u = __float_as_uint(x);
  return (u16)((u + 0x7fffu + ((u >> 16) & 1u)) >> 16);
}
__device__ __forceinline__ u16 f2h(float x) {
  union { _Float16 h; u16 u; } z;
  z.h = (_Float16)x;
  return z.u;
}
__device__ __forceinline__ float h2f(u16 v) {
  union { _Float16 h; u16 u; } z;
  z.u = v;
  return (float)z.h;
}

__device__ __forceinline__ void gload16(const void* g, void* l) {
  __builtin_amdgcn_global_load_lds(
      (const __attribute__((address_space(1))) unsigned int*)g,
      (__attribute__((address_space(3))) unsigned int*)l, 16, 0, 0);
}

__device__ __forceinline__ float wave_red_sum(float v) {
#pragma unroll
  for (int off = 32; off > 0; off >>= 1) v += __shfl_xor(v, off, 64);
  return v;
}
__device__ __forceinline__ float wave_red_max(float v) {
#pragma unroll
  for (int off = 32; off > 0; off >>= 1) v = fmaxf(v, __shfl_xor(v, off, 64));
  return v;
}

// ---------------- stats: per (b,c) mean + rstd over N_ (unbiased, eps 1e-5)
__global__ __launch_bounds__(256) void row_stats_k(const float* __restrict__ x,
                                                   float* __restrict__ mean,
                                                   float* __restrict__ rstd) {
  long row = blockIdx.x;
  const float* p = x + row * (long)N_;
  int t = threadIdx.x;
  float s = 0.f, ss = 0.f;
  for (int i = t * 4; i < N_; i += 1024) {
    float4 v = *(const float4*)(p + i);
    s += v.x + v.y + v.z + v.w;
    ss += v.x * v.x + v.y * v.y + v.z * v.z + v.w * v.w;
  }
  __shared__ float rs_[4], rss_[4];
  int wid = t >> 6, lane = t & 63;
  s = wave_red_sum(s);
  ss = wave_red_sum(ss);
  if (lane == 0) { rs_[wid] = s; rss_[wid] = ss; }
  __syncthreads();
  if (t == 0) {
    float S = rs_[0] + rs_[1] + rs_[2] + rs_[3];
    float SS = rss_[0] + rss_[1] + rss_[2] + rss_[3];
    float m = S / (float)N_;
    float var = (SS - (float)N_ * m * m) / (float)(N_ - 1);
    mean[row] = m;
    rstd[row] = rsqrtf(var + 1e-5f);
  }
}

// ---------------- 3x fp32 arrays -> bf16 planes (one launch)
__global__ __launch_bounds__(256) void cvt3_k(
    const float* __restrict__ a, const float* __restrict__ b,
    const float* __restrict__ c, u16* __restrict__ oa, u16* __restrict__ ob,
    u16* __restrict__ oc, long n) {
  const float* in = blockIdx.y == 0 ? a : (blockIdx.y == 1 ? b : c);
  u16* o = blockIdx.y == 0 ? oa : (blockIdx.y == 1 ? ob : oc);
  long i = ((long)blockIdx.x * 256 + threadIdx.x) * 4;
  if (i >= n) return;
  float4 v = *(const float4*)(in + i);
  *(ushort4*)(o + i) = make_ushort4(f2bf(v.x), f2bf(v.y), f2bf(v.z), f2bf(v.w));
}

// ---------------- transpose+MVN->bf16: X fp32 [C,N] -> o1 = mvn(X)^T [N,C];
// optionally o2 = X^T [N,C]
template <bool HAS2>
__global__ __launch_bounds__(256) void t_cvt_k(
    const float* __restrict__ X, const float* __restrict__ mean,
    const float* __restrict__ rstd, u16* __restrict__ o1,
    u16* __restrict__ o2) {
  __shared__ float tile[64][68];
  const int b = blockIdx.z;
  const int c0 = blockIdx.y * 64, i0 = blockIdx.x * 64;
  const int t = threadIdx.x;
  const int tr = t >> 4, tc = (t & 15) << 2;
  const long CN = (long)C_ * N_;
  const float* Xb = X + (long)b * CN;
#pragma unroll
  for (int p2 = 0; p2 < 4; ++p2) {
    int c = p2 * 16 + tr;
    float4 v = *(const float4*)(Xb + (long)(c0 + c) * N_ + i0 + tc);
    tile[c][tc] = v.x;
    tile[c][tc + 1] = v.y;
    tile[c][tc + 2] = v.z;
    tile[c][tc + 3] = v.w;
  }
  __syncthreads();
  float mv[4], rv[4];
#pragma unroll
  for (int j = 0; j < 4; ++j) {
    mv[j] = mean[b * C_ + c0 + tc + j];
    rv[j] = rstd[b * C_ + c0 + tc + j];
  }
#pragma unroll
  for (int p2 = 0; p2 < 4; ++p2) {
    int ir = p2 * 16 + tr;
    long off = (long)b * CN + (long)(i0 + ir) * C_ + c0 + tc;
    u16 h1[4], h2[4];
#pragma unroll
    for (int j = 0; j < 4; ++j) {
      float v = tile[tc + j][ir];
      if (HAS2) h2[j] = f2bf(v);
      h1[j] = f2bf((v - mv[j]) * rv[j]);
    }
    *(ushort4*)(o1 + off) = make_ushort4(h1[0], h1[1], h1[2], h1[3]);
    if (HAS2) *(ushort4*)(o2 + off) = make_ushort4(h2[0], h2[1], h2[2], h2[3]);
  }
}

// ---------------- softmax over rows of 4096 f16 -> bf16 plane
__global__ __launch_bounds__(256) void softmax_bf_k(const u16* __restrict__ E,
                                                    u16* __restrict__ ph) {
  long row = blockIdx.x;
  const u16* p = E + row * (long)N_;
  int t = threadIdx.x;
  float v[16];
  float mx = -3.4e38f;
#pragma unroll
  for (int q = 0; q < 4; ++q) {
    ushort4 w4 = *(const ushort4*)(p + t * 16 + q * 4);
    v[q * 4 + 0] = h2f(w4.x);
    v[q * 4 + 1] = h2f(w4.y);
    v[q * 4 + 2] = h2f(w4.z);
    v[q * 4 + 3] = h2f(w4.w);
    mx = fmaxf(mx, fmaxf(fmaxf(v[q * 4], v[q * 4 + 1]),
                         fmaxf(v[q * 4 + 2], v[q * 4 + 3])));
  }
  __shared__ float red[4];
  int wid = t >> 6, lane = t & 63;
  mx = wave_red_max(mx);
  if (lane == 0) red[wid] = mx;
  __syncthreads();
  mx = fmaxf(fmaxf(red[0], red[1]), fmaxf(red[2], red[3]));
  float s = 0.f;
#pragma unroll
  for (int i = 0; i < 16; ++i) {
    v[i] = __expf(v[i] - mx);
    s += v[i];
  }
  __syncthreads();
  s = wave_red_sum(s);
  if (lane == 0) red[wid] = s;
  __syncthreads();
  s = red[0] + red[1] + red[2] + red[3];
  float inv = 1.f / s;
  long ob = row * (long)N_ + t * 16;
#pragma unroll
  for (int q = 0; q < 4; ++q) {
    *(ushort4*)(ph + ob + q * 4) =
        make_ushort4(f2bf(v[q * 4 + 0] * inv), f2bf(v[q * 4 + 1] * inv),
                     f2bf(v[q * 4 + 2] * inv), f2bf(v[q * 4 + 3] * inv));
  }
}

// ---------------- style softmax: rows of 512, write TRANSPOSED bf16
__global__ __launch_bounds__(256) void softmax_t_k(const float* __restrict__ E2,
                                                   u16* __restrict__ ph) {
  int b = blockIdx.x >> 9;
  int x = blockIdx.x & 511;
  const float* p = E2 + ((long)b * C_ + x) * C_;
  int t = threadIdx.x;
  float v0 = p[t * 2], v1 = p[t * 2 + 1];
  float mx = fmaxf(v0, v1);
  __shared__ float red[4];
  int wid = t >> 6, lane = t & 63;
  mx = wave_red_max(mx);
  if (lane == 0) red[wid] = mx;
  __syncthreads();
  mx = fmaxf(fmaxf(red[0], red[1]), fmaxf(red[2], red[3]));
  v0 = __expf(v0 - mx);
  v1 = __expf(v1 - mx);
  float s = v0 + v1;
  __syncthreads();
  s = wave_red_sum(s);
  if (lane == 0) red[wid] = s;
  __syncthreads();
  s = red[0] + red[1] + red[2] + red[3];
  float inv = 1.f / s;
  long base = (long)b * C_ * C_;
  ph[base + (long)(t * 2) * C_ + x] = f2bf(v0 * inv);
  ph[base + (long)(t * 2 + 1) * C_ + x] = f2bf(v1 * inv);
}

// ---------------- split-K reduction: sum nsplit fp32 partials -> f32
__global__ __launch_bounds__(256) void redk_k(const float* __restrict__ P,
                                              long pKS, long perB, int nsplit,
                                              float* __restrict__ of,
                                              long total) {
  long e = ((long)blockIdx.x * 256 + threadIdx.x) * 4;
  if (e >= total) return;
  long b = e / perB, rem = e - b * perB;
  const float* p0 = P + b * perB + rem;
  float4 s = *(const float4*)p0;
  for (int k = 1; k < nsplit; ++k) {
    float4 t = *(const float4*)(p0 + (long)k * pKS);
    s.x += t.x;
    s.y += t.y;
    s.z += t.z;
    s.w += t.w;
  }
  *(float4*)(of + b * perB + rem) = s;
}

// ---------------- bf16 MFMA NT GEMM (m97 structure, XCD-swizzled grid) -----
// C[b][m][n] = sum_k A[m,k]*B[n,k]; A,B bf16, K-contiguous rows.
// OUTM: 0 = fp32 (+res), 1 = bf16, 2 = f16. BIAS: 0 none, 1 per-m, 2 per-n.
// 1D grid of nx*ny*nz blocks; id = xcd + 8*(x + nx*g), row = xcd + 8*g,
// by = row % ny, bz = row / ny. All nx x-blocks of one (by,bz) are id%8-equal
// -> same XCD -> A-tile (128 rows) fetched once into that XCD's L2.
template <int OUTM, int BIAS, bool RES>
__global__ __launch_bounds__(256, 3) void mm_k(
    const u16* __restrict__ Ap, long aBS, int lda,
    const u16* __restrict__ Bp, long bBS, int ldb,
    float* Of, u16* __restrict__ Obf, long oBS, long oKS, int ldo,
    const float* __restrict__ bias, const float* resp, long rBS,
    int K, int nsplit, int nx, int ny) {
  __shared__ u16 lds[16384];  // 32KB: A at 0, B at 8192 (u16 units)
  const int id = blockIdx.x;
  const int xcd = id & 7;
  const int rest = id >> 3;
  const int bx = rest % nx;
  const int g = rest / nx;
  const int row = xcd + (g << 3);
  const int by = row % ny;
  const int bz = row / ny;
  const int b = bz / nsplit;
  const int ks = bz % nsplit;
  const int Kc = K / nsplit;
  const int k0beg = ks * Kc;
  const int m0 = by * TM, n0 = bx * TN;
  const int t = threadIdx.x, lane = t & 63, wid = t >> 6;
  const int wm = (wid >> 1) * 64, wn = (wid & 1) * 64;

  // staging assignment: wave 0/1 -> A rows 0-63/64-127; wave 2/3 -> B
  const u16* srcp = (wid < 2) ? (Ap + (long)b * aBS) : (Bp + (long)b * bBS);
  const int sld = (wid < 2) ? lda : ldb;
  const long srow0 = ((wid < 2) ? m0 : n0) + (wid & 1) * 64;
  u16* dstb = &lds[wid * 4096];
  const int srg = lane >> 3;   // row within 8-row group
  const int ssl = lane & 7;    // 16B slot within 128B row

  f4v acc[4][4];
#pragma unroll
  for (int i = 0; i < 4; ++i)
#pragma unroll
    for (int j = 0; j < 4; ++j) acc[i][j] = (f4v){0.f, 0.f, 0.f, 0.f};

  const int lr = lane & 15, ksl = lane >> 4;
  const u16* lA = &lds[0];
  const u16* lB = &lds[8192];

  for (int k0 = k0beg; k0 < k0beg + Kc; k0 += 64) {
#pragma unroll
    for (int s = 0; s < 8; ++s) {
      int r = s * 8 + srg;
      int kb = ((ssl ^ (r & 7)) << 4);  // pre-swizzled byte offset
      const u16* gp = srcp + (srow0 + r) * (long)sld + k0;
      gload16((const char*)gp + kb, dstb + s * 512);
    }
    __syncthreads();
#pragma unroll
    for (int kk = 0; kk < 2; ++kk) {
      s8v ar[4], br[4];
#pragma unroll
      for (int f = 0; f < 4; ++f) {
        int ra = wm + f * 16 + lr;
        ar[f] = *(const s8v*)(lA + ra * 64 +
                              ((((kk << 2) | ksl) ^ (ra & 7)) << 3));
        int rb = wn + f * 16 + lr;
        br[f] = *(const s8v*)(lB + rb * 64 +
                              ((((kk << 2) | ksl) ^ (rb & 7)) << 3));
      }
#pragma unroll
      for (int i = 0; i < 4; ++i)
#pragma unroll
        for (int j = 0; j < 4; ++j)
          acc[i][j] = __builtin_amdgcn_mfma_f32_16x16x32_bf16(
              ar[i], br[j], acc[i][j], 0, 0, 0);
    }
    __syncthreads();
  }

  // ---- direct scalar-store epilogue (known-good) --------------------------
  const float* resb = RES ? (resp + (long)b * rBS) : nullptr;
  long obase = (long)b * oBS + (long)ks * oKS;
#pragma unroll
  for (int i = 0; i < 4; ++i) {
#pragma unroll
    for (int j = 0; j < 4; ++j) {
#pragma unroll
      for (int e = 0; e < 4; ++e) {
        int m = m0 + wm + i * 16 + ksl * 4 + e;
        int n = n0 + wn + j * 16 + lr;
        float v = acc[i][j][e];
        if (BIAS == 1) v += bias[m];
        if (BIAS == 2) v += bias[n];
        long o = obase + (long)m * ldo + n;
        if (OUTM == 0) {
          if (RES) v += resb[(long)m * ldo + n];
          Of[o] = v;
        } else if (OUTM == 1) {
          Obf[o] = f2bf(v);
        } else {
          Obf[o] = f2h(v);
        }
      }
    }
  }
}

// ===========================================================================
extern "C" void kernel_launch(void* const* d_in, const int* in_sizes, int n_in,
                              void* d_out, int out_size, void* d_ws,
                              size_t ws_size, hipStream_t stream) {
  (void)in_sizes; (void)n_in; (void)out_size;
  const long CN = (long)C_ * N_;
  const long CC = (long)C_ * C_;

  const float* xc = (const float*)d_in[0];
  const float* xs = (const float*)d_in[1];
  const float* cw = (const float*)d_in[2];
  const float* cb = (const float*)d_in[3];
  const float* sw = (const float*)d_in[4];
  const float* sb = (const float*)d_in[5];
  const float* aw = (const float*)d_in[6];
  const float* ab = (const float*)d_in[7];
  float* out = (float*)d_out;

  char* w = (char*)d_ws;
  auto carve = [&](size_t bytes) {
    char* r = w;
    w += (bytes + 255) & ~(size_t)255;
    return r;
  };
  u16* cwb = (u16*)carve(4 * CC * 2);
  u16* swb = (u16*)carve(4 * CC * 2);
  u16* awb = (u16*)carve(4 * CC * 2);
  float* stats = (float*)carve(8 * B_ * C_ * 4);
  float* m1 = stats, *r1 = m1 + B_ * C_, *m2 = r1 + B_ * C_, *r2 = m2 + B_ * C_;
  float* m3 = r2 + B_ * C_, *r3 = m3 + B_ * C_, *m4 = r3 + B_ * C_,
       *r4 = m4 + B_ * C_;
  float* E2buf = (float*)carve(B_ * CC * 4);
  u16* aT = (u16*)carve(B_ * CC * 2);
  const size_t SLOT = (size_t)B_ * CN * 4;  // 33.5MB
  char* s0 = carve(SLOT);
  char* s1 = carve(SLOT);
  char* s2 = carve(SLOT);
  char* s3 = carve(SLOT);
  size_t used = (size_t)(w - (char*)d_ws);
  // energy f16 (2B) + attn bf16 (2B) per element
  int S = N_;
  while (S > 128 && used + (size_t)4 * B_ * S * N_ > ws_size) S >>= 1;
  u16* Ereg16 = (u16*)carve((size_t)B_ * S * N_ * 2);
  u16* atB = (u16*)carve((size_t)B_ * S * N_ * 2);
  float* EregF = (float*)Ereg16;  // reused for E2 split-K fp32 partials (32MB)

  u16* sA = (u16*)s0;
  u16* sB = (u16*)s1;
  u16* sC = (u16*)s2;
  u16* sD = (u16*)s3;

  const int e2s = 8;

  dim3 blk(256);
  // 1D swizzled grids: total = nx*ny*nz; pass (nx, ny) to mm_k.
  auto g1 = [](int nx, int ny, int nz) { return dim3(nx * ny * nz); };
  dim3 gTs(N_ / 64, C_ / 64, B_);

  // weights -> bf16 (one launch)
  cvt3_k<<<dim3(1024, 3), blk, 0, stream>>>(cw, sw, aw, cwb, swb, awb, 4 * CC);

  // Attention: E(f16) = Q·K^T -> softmax(bf16) -> oT = attn·V^T (direct)
  auto attention = [&](const u16* Qp, int ldq, long qBS, const u16* Kp,
                       int ldk, long kBS, const u16* Vp, u16* oT) {
    for (int i0 = 0; i0 < N_; i0 += S) {
      mm_k<2, 0, false><<<g1(N_ / TN, S / TM, B_), blk, 0, stream>>>(
          Qp + (long)i0 * ldq, qBS, ldq, Kp, kBS, ldk, nullptr, Ereg16,
          (long)S * N_, 0, N_, nullptr, nullptr, 0, C_, 1, N_ / TN, S / TM);
      softmax_bf_k<<<B_ * S, blk, 0, stream>>>(Ereg16, atB);
      mm_k<1, 0, false><<<g1(C_ / TN, S / TM, B_), blk, 0, stream>>>(
          atB, (long)S * N_, N_, Vp, CN, N_, nullptr, oT + (long)i0 * C_, CN,
          0, C_, nullptr, nullptr, 0, N_, 1, C_ / TN, S / TM);
    }
  };

  // ===================== Module 1: content self-attn =======================
  row_stats_k<<<B_ * C_, blk, 0, stream>>>(xc, m1, r1);
  row_stats_k<<<B_ * C_, blk, 0, stream>>>(xs, m2, r2);  // hoisted (module 2)
  t_cvt_k<true><<<gTs, blk, 0, stream>>>(xc, m1, r1, sA, sB);  // xnT, xT
  // fused Q|K: A=xnT, B=[W0;W1] (1024 rows of cwb), out sC as [N,1024]
  mm_k<1, 2, false><<<g1(8, 32, B_), blk, 0, stream>>>(sA, CN, C_, cwb, 0, C_,
      nullptr, sC, (long)N_ * 1024, 0, 1024, cb, nullptr, 0, C_, 1, 8, 32);
  // V1 [C,N] (sD): A=W2, B=xT
  mm_k<1, 1, false><<<g1(32, 4, B_), blk, 0, stream>>>(cwb + 2 * CC, 0, C_,
      sB, CN, C_, nullptr, sD, CN, 0, N_, cb + 2 * C_, nullptr, 0, C_, 1, 32,
      4);
  attention(sC, 1024, (long)N_ * 1024, sC + 512, 1024, (long)N_ * 1024, sD,
            sA);  // o1T -> sA
  // cf = W3·o1 + b3 + x -> d_out (fp32 [C,N])
  mm_k<0, 1, true><<<g1(32, 4, B_), blk, 0, stream>>>(cwb + 3 * CC, 0, C_, sA,
      CN, C_, out, nullptr, CN, 0, N_, cb + 3 * C_, xc, CN, C_, 1, 32, 4);

  // ===================== Module 2: style self-attn (channel) ===============
  t_cvt_k<true><<<gTs, blk, 0, stream>>>(xs, m2, r2, sA, sC);  // snT, sT
  // fused f|g: A=[W0s;W1s] (1024 rows of swb), B=sT, out sD as [1024,N]
  mm_k<1, 1, false><<<g1(32, 8, B_), blk, 0, stream>>>(swb, 0, C_, sC, CN, C_,
      nullptr, sD, (long)1024 * N_, 0, N_, sb, nullptr, 0, C_, 1, 32, 8);
  // hT[i,d] (sB): A=snT, B=W2s
  mm_k<1, 2, false><<<g1(4, 32, B_), blk, 0, stream>>>(sA, CN, C_,
      swb + 2 * CC, 0, C_, nullptr, sB, CN, 0, C_, sb + 2 * C_, nullptr, 0,
      C_, 1, 4, 32);
  // E2[c,d] = f[c,:]·g[d,:] over N (split-K fp32 partials in EregF)
  mm_k<0, 0, false><<<g1(4, 4, B_ * e2s), blk, 0, stream>>>(
      sD, (long)1024 * N_, N_, sD + (long)512 * N_, (long)1024 * N_, N_,
      EregF, nullptr, CC, (long)B_ * CC, C_, nullptr, nullptr, 0, N_, e2s, 4,
      4);
  redk_k<<<(B_ * (int)CC) / 1024, blk, 0, stream>>>(
      EregF, (long)B_ * CC, CC, e2s, E2buf, (long)B_ * CC);
  softmax_t_k<<<B_ * C_, blk, 0, stream>>>(E2buf, aT);
  // o2T[i,c] (sA): A=hT [N,C], B=attnT [C,C]
  mm_k<1, 0, false><<<g1(4, 32, B_), blk, 0, stream>>>(sB, CN, C_, aT, CC, C_,
      nullptr, sA, CN, 0, C_, nullptr, nullptr, 0, C_, 1, 4, 32);
  // sf = W3s·o2 + b3s + s -> sB as fp32 [C,N]
  float* sfF = (float*)s1;
  mm_k<0, 1, true><<<g1(32, 4, B_), blk, 0, stream>>>(swb + 3 * CC, 0, C_, sA,
      CN, C_, sfF, nullptr, CN, 0, N_, sb + 3 * C_, xs, CN, C_, 1, 32, 4);

  // ===================== Module 3: cross attention =========================
  row_stats_k<<<B_ * C_, blk, 0, stream>>>(out, m3, r3);
  row_stats_k<<<B_ * C_, blk, 0, stream>>>(sfF, m4, r4);
  t_cvt_k<false><<<gTs, blk, 0, stream>>>(out, m3, r3, sC, nullptr);  // cfnT
  t_cvt_k<true><<<gTs, blk, 0, stream>>>(sfF, m4, r4, sD, sA);  // sfnT, sfT
  // Q3 (sB): A=cfnT, B=W0a ; K3 (sC): A=sfnT, B=W1a
  mm_k<1, 2, false><<<g1(4, 32, B_), blk, 0, stream>>>(sC, CN, C_, awb, 0, C_,
      nullptr, sB, CN, 0, C_, ab, nullptr, 0, C_, 1, 4, 32);
  mm_k<1, 2, false><<<g1(4, 32, B_), blk, 0, stream>>>(sD, CN, C_, awb + CC,
      0, C_, nullptr, sC, CN, 0, C_, ab + C_, nullptr, 0, C_, 1, 4, 32);
  // V3 [C,N] (sD): A=W2a, B=sfT
  mm_k<1, 1, false><<<g1(32, 4, B_), blk, 0, stream>>>(awb + 2 * CC, 0, C_,
      sA, CN, C_, nullptr, sD, CN, 0, N_, ab + 2 * C_, nullptr, 0, C_, 1, 32,
      4);
  attention(sB, C_, CN, sC, C_, CN, sD, sA);  // o3T -> sA
  // out = W3a·o3 + b3a + cf (in-place residual on d_out)
  mm_k<0, 1, true><<<g1(32, 4, B_), blk, 0, stream>>>(awb + 3 * CC, 0, C_, sA,
      CN, C_, out, nullptr, CN, 0, N_, ab + 3 * C_, out, CN, C_, 1, 32, 4);
}

// Round 10
// 1084.956 us; speedup vs baseline: 1.0811x; 1.0811x over previous
//
#include <hip/hip_runtime.h>
#include <math.h>

// Multi_Adaptation_Module on MI355X. Round 10 = Round 8 (passing, no swizzle)
// + bf16 cf/sf intermediates: projections write bf16 [C,N] (67->17 MB),
// stats/t_cvt read bf16, final residual reads cf as bf16. d_out written once.
// mm_k residual generalized: RESM 0=none, 1=fp32, 2=bf16.

#define B_ 4
#define C_ 512
#define N_ 4096
#define TM 128
#define TN 128

typedef unsigned short u16;
typedef __attribute__((ext_vector_type(8))) short s8v;   // 8 bf16 (4 VGPR)
typedef __attribute__((ext_vector_type(4))) float f4v;

__device__ __forceinline__ u16 f2bf(float x) {
  unsigned u = __float_as_uint(x);
  return (u16)((u + 0x7fffu + ((u >> 16) & 1u)) >> 16);
}
__device__ __forceinline__ float bf2f(u16 h) {
  return __uint_as_float(((unsigned)h) << 16);
}
__device__ __forceinline__ u16 f2h(float x) {
  union { _Float16 h; u16 u; } z;
  z.h = (_Float16)x;
  return z.u;
}
__device__ __forceinline__ float h2f(u16 v) {
  union { _Float16 h; u16 u; } z;
  z.u = v;
  return (float)z.h;
}

__device__ __forceinline__ void gload16(const void* g, void* l) {
  __builtin_amdgcn_global_load_lds(
      (const __attribute__((address_space(1))) unsigned int*)g,
      (__attribute__((address_space(3))) unsigned int*)l, 16, 0, 0);
}

__device__ __forceinline__ float wave_red_sum(float v) {
#pragma unroll
  for (int off = 32; off > 0; off >>= 1) v += __shfl_xor(v, off, 64);
  return v;
}
__device__ __forceinline__ float wave_red_max(float v) {
#pragma unroll
  for (int off = 32; off > 0; off >>= 1) v = fmaxf(v, __shfl_xor(v, off, 64));
  return v;
}

// ---------------- stats over N_ (unbiased var, eps 1e-5), fp32 input
__global__ __launch_bounds__(256) void row_stats_k(const float* __restrict__ x,
                                                   float* __restrict__ mean,
                                                   float* __restrict__ rstd) {
  long row = blockIdx.x;
  const float* p = x + row * (long)N_;
  int t = threadIdx.x;
  float s = 0.f, ss = 0.f;
  for (int i = t * 4; i < N_; i += 1024) {
    float4 v = *(const float4*)(p + i);
    s += v.x + v.y + v.z + v.w;
    ss += v.x * v.x + v.y * v.y + v.z * v.z + v.w * v.w;
  }
  __shared__ float rs_[4], rss_[4];
  int wid = t >> 6, lane = t & 63;
  s = wave_red_sum(s);
  ss = wave_red_sum(ss);
  if (lane == 0) { rs_[wid] = s; rss_[wid] = ss; }
  __syncthreads();
  if (t == 0) {
    float S = rs_[0] + rs_[1] + rs_[2] + rs_[3];
    float SS = rss_[0] + rss_[1] + rss_[2] + rss_[3];
    float m = S / (float)N_;
    float var = (SS - (float)N_ * m * m) / (float)(N_ - 1);
    mean[row] = m;
    rstd[row] = rsqrtf(var + 1e-5f);
  }
}

// ---------------- stats, bf16 input (ushort8 = 16B/lane loads)
__global__ __launch_bounds__(256) void row_stats_bf_k(
    const u16* __restrict__ x, float* __restrict__ mean,
    float* __restrict__ rstd) {
  long row = blockIdx.x;
  const u16* p = x + row * (long)N_;
  int t = threadIdx.x;
  float s = 0.f, ss = 0.f;
  for (int i = t * 8; i < N_; i += 2048) {
    ushort4 a = *(const ushort4*)(p + i);
    ushort4 b = *(const ushort4*)(p + i + 4);
    float v0 = bf2f(a.x), v1 = bf2f(a.y), v2 = bf2f(a.z), v3 = bf2f(a.w);
    float v4 = bf2f(b.x), v5 = bf2f(b.y), v6 = bf2f(b.z), v7 = bf2f(b.w);
    s += v0 + v1 + v2 + v3 + v4 + v5 + v6 + v7;
    ss += v0 * v0 + v1 * v1 + v2 * v2 + v3 * v3 + v4 * v4 + v5 * v5 +
          v6 * v6 + v7 * v7;
  }
  __shared__ float rs_[4], rss_[4];
  int wid = t >> 6, lane = t & 63;
  s = wave_red_sum(s);
  ss = wave_red_sum(ss);
  if (lane == 0) { rs_[wid] = s; rss_[wid] = ss; }
  __syncthreads();
  if (t == 0) {
    float S = rs_[0] + rs_[1] + rs_[2] + rs_[3];
    float SS = rss_[0] + rss_[1] + rss_[2] + rss_[3];
    float m = S / (float)N_;
    float var = (SS - (float)N_ * m * m) / (float)(N_ - 1);
    mean[row] = m;
    rstd[row] = rsqrtf(var + 1e-5f);
  }
}

// ---------------- 3x fp32 arrays -> bf16 planes (one launch)
__global__ __launch_bounds__(256) void cvt3_k(
    const float* __restrict__ a, const float* __restrict__ b,
    const float* __restrict__ c, u16* __restrict__ oa, u16* __restrict__ ob,
    u16* __restrict__ oc, long n) {
  const float* in = blockIdx.y == 0 ? a : (blockIdx.y == 1 ? b : c);
  u16* o = blockIdx.y == 0 ? oa : (blockIdx.y == 1 ? ob : oc);
  long i = ((long)blockIdx.x * 256 + threadIdx.x) * 4;
  if (i >= n) return;
  float4 v = *(const float4*)(in + i);
  *(ushort4*)(o + i) = make_ushort4(f2bf(v.x), f2bf(v.y), f2bf(v.z), f2bf(v.w));
}

// ---------------- transpose+MVN->bf16 from fp32 [C,N]
template <bool HAS2>
__global__ __launch_bounds__(256) void t_cvt_k(
    const float* __restrict__ X, const float* __restrict__ mean,
    const float* __restrict__ rstd, u16* __restrict__ o1,
    u16* __restrict__ o2) {
  __shared__ float tile[64][68];
  const int b = blockIdx.z;
  const int c0 = blockIdx.y * 64, i0 = blockIdx.x * 64;
  const int t = threadIdx.x;
  const int tr = t >> 4, tc = (t & 15) << 2;
  const long CN = (long)C_ * N_;
  const float* Xb = X + (long)b * CN;
#pragma unroll
  for (int p2 = 0; p2 < 4; ++p2) {
    int c = p2 * 16 + tr;
    float4 v = *(const float4*)(Xb + (long)(c0 + c) * N_ + i0 + tc);
    tile[c][tc] = v.x;
    tile[c][tc + 1] = v.y;
    tile[c][tc + 2] = v.z;
    tile[c][tc + 3] = v.w;
  }
  __syncthreads();
  float mv[4], rv[4];
#pragma unroll
  for (int j = 0; j < 4; ++j) {
    mv[j] = mean[b * C_ + c0 + tc + j];
    rv[j] = rstd[b * C_ + c0 + tc + j];
  }
#pragma unroll
  for (int p2 = 0; p2 < 4; ++p2) {
    int ir = p2 * 16 + tr;
    long off = (long)b * CN + (long)(i0 + ir) * C_ + c0 + tc;
    u16 h1[4], h2[4];
#pragma unroll
    for (int j = 0; j < 4; ++j) {
      float v = tile[tc + j][ir];
      if (HAS2) h2[j] = f2bf(v);
      h1[j] = f2bf((v - mv[j]) * rv[j]);
    }
    *(ushort4*)(o1 + off) = make_ushort4(h1[0], h1[1], h1[2], h1[3]);
    if (HAS2) *(ushort4*)(o2 + off) = make_ushort4(h2[0], h2[1], h2[2], h2[3]);
  }
}

// ---------------- transpose+MVN->bf16 from bf16 [C,N]
template <bool HAS2>
__global__ __launch_bounds__(256) void t_cvt_bf_k(
    const u16* __restrict__ X, const float* __restrict__ mean,
    const float* __restrict__ rstd, u16* __restrict__ o1,
    u16* __restrict__ o2) {
  __shared__ float tile[64][68];
  const int b = blockIdx.z;
  const int c0 = blockIdx.y * 64, i0 = blockIdx.x * 64;
  const int t = threadIdx.x;
  const int tr = t >> 4, tc = (t & 15) << 2;
  const long CN = (long)C_ * N_;
  const u16* Xb = X + (long)b * CN;
#pragma unroll
  for (int p2 = 0; p2 < 4; ++p2) {
    int c = p2 * 16 + tr;
    ushort4 v = *(const ushort4*)(Xb + (long)(c0 + c) * N_ + i0 + tc);
    tile[c][tc] = bf2f(v.x);
    tile[c][tc + 1] = bf2f(v.y);
    tile[c][tc + 2] = bf2f(v.z);
    tile[c][tc + 3] = bf2f(v.w);
  }
  __syncthreads();
  float mv[4], rv[4];
#pragma unroll
  for (int j = 0; j < 4; ++j) {
    mv[j] = mean[b * C_ + c0 + tc + j];
    rv[j] = rstd[b * C_ + c0 + tc + j];
  }
#pragma unroll
  for (int p2 = 0; p2 < 4; ++p2) {
    int ir = p2 * 16 + tr;
    long off = (long)b * CN + (long)(i0 + ir) * C_ + c0 + tc;
    u16 h1[4], h2[4];
#pragma unroll
    for (int j = 0; j < 4; ++j) {
      float v = tile[tc + j][ir];
      if (HAS2) h2[j] = f2bf(v);
      h1[j] = f2bf((v - mv[j]) * rv[j]);
    }
    *(ushort4*)(o1 + off) = make_ushort4(h1[0], h1[1], h1[2], h1[3]);
    if (HAS2) *(ushort4*)(o2 + off) = make_ushort4(h2[0], h2[1], h2[2], h2[3]);
  }
}

// ---------------- softmax over rows of 4096 f16 -> bf16 plane
__global__ __launch_bounds__(256) void softmax_bf_k(const u16* __restrict__ E,
                                                    u16* __restrict__ ph) {
  long row = blockIdx.x;
  const u16* p = E + row * (long)N_;
  int t = threadIdx.x;
  float v[16];
  float mx = -3.4e38f;
#pragma unroll
  for (int q = 0; q < 4; ++q) {
    ushort4 w4 = *(const ushort4*)(p + t * 16 + q * 4);
    v[q * 4 + 0] = h2f(w4.x);
    v[q * 4 + 1] = h2f(w4.y);
    v[q * 4 + 2] = h2f(w4.z);
    v[q * 4 + 3] = h2f(w4.w);
    mx = fmaxf(mx, fmaxf(fmaxf(v[q * 4], v[q * 4 + 1]),
                         fmaxf(v[q * 4 + 2], v[q * 4 + 3])));
  }
  __shared__ float red[4];
  int wid = t >> 6, lane = t & 63;
  mx = wave_red_max(mx);
  if (lane == 0) red[wid] = mx;
  __syncthreads();
  mx = fmaxf(fmaxf(red[0], red[1]), fmaxf(red[2], red[3]));
  float s = 0.f;
#pragma unroll
  for (int i = 0; i < 16; ++i) {
    v[i] = __expf(v[i] - mx);
    s += v[i];
  }
  __syncthreads();
  s = wave_red_sum(s);
  if (lane == 0) red[wid] = s;
  __syncthreads();
  s = red[0] + red[1] + red[2] + red[3];
  float inv = 1.f / s;
  long ob = row * (long)N_ + t * 16;
#pragma unroll
  for (int q = 0; q < 4; ++q) {
    *(ushort4*)(ph + ob + q * 4) =
        make_ushort4(f2bf(v[q * 4 + 0] * inv), f2bf(v[q * 4 + 1] * inv),
                     f2bf(v[q * 4 + 2] * inv), f2bf(v[q * 4 + 3] * inv));
  }
}

// ---------------- style softmax: rows of 512, write TRANSPOSED bf16
__global__ __launch_bounds__(256) void softmax_t_k(const float* __restrict__ E2,
                                                   u16* __restrict__ ph) {
  int b = blockIdx.x >> 9;
  int x = blockIdx.x & 511;
  const float* p = E2 + ((long)b * C_ + x) * C_;
  int t = threadIdx.x;
  float v0 = p[t * 2], v1 = p[t * 2 + 1];
  float mx = fmaxf(v0, v1);
  __shared__ float red[4];
  int wid = t >> 6, lane = t & 63;
  mx = wave_red_max(mx);
  if (lane == 0) red[wid] = mx;
  __syncthreads();
  mx = fmaxf(fmaxf(red[0], red[1]), fmaxf(red[2], red[3]));
  v0 = __expf(v0 - mx);
  v1 = __expf(v1 - mx);
  float s = v0 + v1;
  __syncthreads();
  s = wave_red_sum(s);
  if (lane == 0) red[wid] = s;
  __syncthreads();
  s = red[0] + red[1] + red[2] + red[3];
  float inv = 1.f / s;
  long base = (long)b * C_ * C_;
  ph[base + (long)(t * 2) * C_ + x] = f2bf(v0 * inv);
  ph[base + (long)(t * 2 + 1) * C_ + x] = f2bf(v1 * inv);
}

// ---------------- split-K reduction: sum nsplit fp32 partials -> f32
__global__ __launch_bounds__(256) void redk_k(const float* __restrict__ P,
                                              long pKS, long perB, int nsplit,
                                              float* __restrict__ of,
                                              long total) {
  long e = ((long)blockIdx.x * 256 + threadIdx.x) * 4;
  if (e >= total) return;
  long b = e / perB, rem = e - b * perB;
  const float* p0 = P + b * perB + rem;
  float4 s = *(const float4*)p0;
  for (int k = 1; k < nsplit; ++k) {
    float4 t = *(const float4*)(p0 + (long)k * pKS);
    s.x += t.x;
    s.y += t.y;
    s.z += t.z;
    s.w += t.w;
  }
  *(float4*)(of + b * perB + rem) = s;
}

// ---------------- bf16 MFMA NT GEMM (m97 structure) ------------------------
// C[b][m][n] = sum_k A[m,k]*B[n,k]; A,B bf16, K-contiguous rows.
// OUTM: 0 = fp32, 1 = bf16, 2 = f16. BIAS: 0 none, 1 per-m, 2 per-n.
// RESM: 0 none, 1 fp32 residual (resp), 2 bf16 residual (res16).
template <int OUTM, int BIAS, int RESM>
__global__ __launch_bounds__(256, 3) void mm_k(
    const u16* __restrict__ Ap, long aBS, int lda,
    const u16* __restrict__ Bp, long bBS, int ldb,
    float* Of, u16* __restrict__ Obf, long oBS, long oKS, int ldo,
    const float* __restrict__ bias, const float* resp,
    const u16* __restrict__ res16, long rBS, int K, int nsplit) {
  __shared__ u16 lds[16384];  // 32KB: A at 0, B at 8192 (u16 units)
  const int b = blockIdx.z / nsplit;
  const int ks = blockIdx.z % nsplit;
  const int Kc = K / nsplit;
  const int k0beg = ks * Kc;
  const int m0 = blockIdx.y * TM, n0 = blockIdx.x * TN;
  const int t = threadIdx.x, lane = t & 63, wid = t >> 6;
  const int wm = (wid >> 1) * 64, wn = (wid & 1) * 64;

  const u16* srcp = (wid < 2) ? (Ap + (long)b * aBS) : (Bp + (long)b * bBS);
  const int sld = (wid < 2) ? lda : ldb;
  const long srow0 = ((wid < 2) ? m0 : n0) + (wid & 1) * 64;
  u16* dstb = &lds[wid * 4096];
  const int srg = lane >> 3;
  const int ssl = lane & 7;

  f4v acc[4][4];
#pragma unroll
  for (int i = 0; i < 4; ++i)
#pragma unroll
    for (int j = 0; j < 4; ++j) acc[i][j] = (f4v){0.f, 0.f, 0.f, 0.f};

  const int lr = lane & 15, ksl = lane >> 4;
  const u16* lA = &lds[0];
  const u16* lB = &lds[8192];

  for (int k0 = k0beg; k0 < k0beg + Kc; k0 += 64) {
#pragma unroll
    for (int s = 0; s < 8; ++s) {
      int r = s * 8 + srg;
      int kb = ((ssl ^ (r & 7)) << 4);
      const u16* gp = srcp + (srow0 + r) * (long)sld + k0;
      gload16((const char*)gp + kb, dstb + s * 512);
    }
    __syncthreads();
#pragma unroll
    for (int kk = 0; kk < 2; ++kk) {
      s8v ar[4], br[4];
#pragma unroll
      for (int f = 0; f < 4; ++f) {
        int ra = wm + f * 16 + lr;
        ar[f] = *(const s8v*)(lA + ra * 64 +
                              ((((kk << 2) | ksl) ^ (ra & 7)) << 3));
        int rb = wn + f * 16 + lr;
        br[f] = *(const s8v*)(lB + rb * 64 +
                              ((((kk << 2) | ksl) ^ (rb & 7)) << 3));
      }
#pragma unroll
      for (int i = 0; i < 4; ++i)
#pragma unroll
        for (int j = 0; j < 4; ++j)
          acc[i][j] = __builtin_amdgcn_mfma_f32_16x16x32_bf16(
              ar[i], br[j], acc[i][j], 0, 0, 0);
    }
    __syncthreads();
  }

  // ---- direct scalar-store epilogue (known-good) --------------------------
  const float* resb = (RESM == 1) ? (resp + (long)b * rBS) : nullptr;
  const u16* resb16 = (RESM == 2) ? (res16 + (long)b * rBS) : nullptr;
  long obase = (long)b * oBS + (long)ks * oKS;
#pragma unroll
  for (int i = 0; i < 4; ++i) {
#pragma unroll
    for (int j = 0; j < 4; ++j) {
#pragma unroll
      for (int e = 0; e < 4; ++e) {
        int m = m0 + wm + i * 16 + ksl * 4 + e;
        int n = n0 + wn + j * 16 + lr;
        float v = acc[i][j][e];
        if (BIAS == 1) v += bias[m];
        if (BIAS == 2) v += bias[n];
        if (RESM == 1) v += resb[(long)m * ldo + n];
        if (RESM == 2) v += bf2f(resb16[(long)m * ldo + n]);
        long o = obase + (long)m * ldo + n;
        if (OUTM == 0) {
          Of[o] = v;
        } else if (OUTM == 1) {
          Obf[o] = f2bf(v);
        } else {
          Obf[o] = f2h(v);
        }
      }
    }
  }
}

// ===========================================================================
extern "C" void kernel_launch(void* const* d_in, const int* in_sizes, int n_in,
                              void* d_out, int out_size, void* d_ws,
                              size_t ws_size, hipStream_t stream) {
  (void)in_sizes; (void)n_in; (void)out_size;
  const long CN = (long)C_ * N_;
  const long CC = (long)C_ * C_;

  const float* xc = (const float*)d_in[0];
  const float* xs = (const float*)d_in[1];
  const float* cw = (const float*)d_in[2];
  const float* cb = (const float*)d_in[3];
  const float* sw = (const float*)d_in[4];
  const float* sb = (const float*)d_in[5];
  const float* aw = (const float*)d_in[6];
  const float* ab = (const float*)d_in[7];
  float* out = (float*)d_out;

  char* w = (char*)d_ws;
  auto carve = [&](size_t bytes) {
    char* r = w;
    w += (bytes + 255) & ~(size_t)255;
    return r;
  };
  u16* cwb = (u16*)carve(4 * CC * 2);
  u16* swb = (u16*)carve(4 * CC * 2);
  u16* awb = (u16*)carve(4 * CC * 2);
  float* stats = (float*)carve(8 * B_ * C_ * 4);
  float* m1 = stats, *r1 = m1 + B_ * C_, *m2 = r1 + B_ * C_, *r2 = m2 + B_ * C_;
  float* m3 = r2 + B_ * C_, *r3 = m3 + B_ * C_, *m4 = r3 + B_ * C_,
       *r4 = m4 + B_ * C_;
  float* E2buf = (float*)carve(B_ * CC * 4);
  u16* aT = (u16*)carve(B_ * CC * 2);
  const size_t SLOT = (size_t)B_ * CN * 4;  // 33.5MB
  char* s0 = carve(SLOT);
  char* s1 = carve(SLOT);
  char* s2 = carve(SLOT);
  char* s3 = carve(SLOT);
  size_t used = (size_t)(w - (char*)d_ws);
  int S = N_;
  while (S > 128 && used + (size_t)4 * B_ * S * N_ > ws_size) S >>= 1;
  u16* E16 = (u16*)carve((size_t)B_ * S * N_ * 2);  // f16 energy
  u16* AT = (u16*)carve((size_t)B_ * S * N_ * 2);   // bf16 attn / scratch
  float* EregF = (float*)E16;  // E2 split-K fp32 partials (32MB) reuse

  u16* sA = (u16*)s0;
  u16* sB = (u16*)s1;
  u16* sC = (u16*)s2;
  u16* sD = (u16*)s3;
  // AT-region parking (only while attention is not running):
  u16* at0 = AT;                 // hT (M2) / cfnT (M3)
  u16* at1 = AT + B_ * CN;       // sfnT (M3)
  u16* at2 = AT + 2 * B_ * CN;   // sfT (M3)

  const int e2s = 8;

  dim3 blk(256);
  dim3 gQ(4, 32, B_);     // M=4096, N=512
  dim3 gV(32, 4, B_);     // M=512,  N=4096
  dim3 gQK(8, 32, B_);    // M=4096, N=1024 (fused Q|K)
  dim3 gFG(32, 8, B_);    // M=1024, N=4096 (fused f|g)
  dim3 gTs(N_ / 64, C_ / 64, B_);

  cvt3_k<<<dim3(1024, 3), blk, 0, stream>>>(cw, sw, aw, cwb, swb, awb, 4 * CC);

  // Attention: E(f16) = Q·K^T -> softmax(bf16) -> oT = attn·V^T (direct)
  auto attention = [&](const u16* Qp, int ldq, long qBS, const u16* Kp,
                       int ldk, long kBS, const u16* Vp, u16* oT) {
    for (int i0 = 0; i0 < N_; i0 += S) {
      mm_k<2, 0, 0><<<dim3(N_ / TN, S / TM, B_), blk, 0, stream>>>(
          Qp + (long)i0 * ldq, qBS, ldq, Kp, kBS, ldk, nullptr, E16,
          (long)S * N_, 0, N_, nullptr, nullptr, nullptr, 0, C_, 1);
      softmax_bf_k<<<B_ * S, blk, 0, stream>>>(E16, AT);
      mm_k<1, 0, 0><<<dim3(C_ / TN, S / TM, B_), blk, 0, stream>>>(
          AT, (long)S * N_, N_, Vp, CN, N_, nullptr, oT + (long)i0 * C_, CN,
          0, C_, nullptr, nullptr, nullptr, 0, N_, 1);
    }
  };

  // ===================== Module 1: content self-attn =======================
  row_stats_k<<<B_ * C_, blk, 0, stream>>>(xc, m1, r1);
  row_stats_k<<<B_ * C_, blk, 0, stream>>>(xs, m2, r2);  // hoisted
  t_cvt_k<true><<<gTs, blk, 0, stream>>>(xc, m1, r1, sA, sB);  // xnT, xT
  // fused Q|K -> sC [N,1024]
  mm_k<1, 2, 0><<<gQK, blk, 0, stream>>>(sA, CN, C_, cwb, 0, C_, nullptr, sC,
      (long)N_ * 1024, 0, 1024, cb, nullptr, nullptr, 0, C_, 1);
  // V1 [C,N] -> sD
  mm_k<1, 1, 0><<<gV, blk, 0, stream>>>(cwb + 2 * CC, 0, C_, sB, CN, C_,
      nullptr, sD, CN, 0, N_, cb + 2 * C_, nullptr, nullptr, 0, C_, 1);
  attention(sC, 1024, (long)N_ * 1024, sC + 512, 1024, (long)N_ * 1024, sD,
            sA);  // o1T -> sA
  // cf = W3·o1 + b3 + xc -> sB as BF16 [C,N]
  mm_k<1, 1, 1><<<gV, blk, 0, stream>>>(cwb + 3 * CC, 0, C_, sA, CN, C_,
      nullptr, sB, CN, 0, N_, cb + 3 * C_, xc, nullptr, CN, C_, 1);

  // ===================== Module 2: style self-attn (channel) ===============
  t_cvt_k<true><<<gTs, blk, 0, stream>>>(xs, m2, r2, sA, sC);  // snT, sT
  // fused f|g -> sD [1024,N]
  mm_k<1, 1, 0><<<gFG, blk, 0, stream>>>(swb, 0, C_, sC, CN, C_, nullptr, sD,
      (long)1024 * N_, 0, N_, sb, nullptr, nullptr, 0, C_, 1);
  // hT [N,C] -> at0 (AT region free outside attention)
  mm_k<1, 2, 0><<<gQ, blk, 0, stream>>>(sA, CN, C_, swb + 2 * CC, 0, C_,
      nullptr, at0, CN, 0, C_, sb + 2 * C_, nullptr, nullptr, 0, C_, 1);
  // E2 split-K partials in EregF
  mm_k<0, 0, 0><<<dim3(4, 4, B_ * e2s), blk, 0, stream>>>(
      sD, (long)1024 * N_, N_, sD + (long)512 * N_, (long)1024 * N_, N_,
      EregF, nullptr, CC, (long)B_ * CC, C_, nullptr, nullptr, nullptr, 0, N_,
      e2s);
  redk_k<<<(B_ * (int)CC) / 1024, blk, 0, stream>>>(
      EregF, (long)B_ * CC, CC, e2s, E2buf, (long)B_ * CC);
  softmax_t_k<<<B_ * C_, blk, 0, stream>>>(E2buf, aT);
  // o2T [N,C] -> sA (snT consumed by hT conv)
  mm_k<1, 0, 0><<<gQ, blk, 0, stream>>>(at0, CN, C_, aT, CC, C_, nullptr, sA,
      CN, 0, C_, nullptr, nullptr, nullptr, 0, C_, 1);
  // sf = W3s·o2 + b3s + xs -> sC as BF16 [C,N] (sT consumed by f|g)
  mm_k<1, 1, 1><<<gV, blk, 0, stream>>>(swb + 3 * CC, 0, C_, sA, CN, C_,
      nullptr, sC, CN, 0, N_, sb + 3 * C_, xs, nullptr, CN, C_, 1);

  // ===================== Module 3: cross attention =========================
  row_stats_bf_k<<<B_ * C_, blk, 0, stream>>>(sB, m3, r3);  // cf stats
  row_stats_bf_k<<<B_ * C_, blk, 0, stream>>>(sC, m4, r4);  // sf stats
  t_cvt_bf_k<false><<<gTs, blk, 0, stream>>>(sB, m3, r3, at0, nullptr); // cfnT
  t_cvt_bf_k<true><<<gTs, blk, 0, stream>>>(sC, m4, r4, at1, at2); // sfnT,sfT
  // Q3 [N,C] -> sD (fg dead)
  mm_k<1, 2, 0><<<gQ, blk, 0, stream>>>(at0, CN, C_, awb, 0, C_, nullptr, sD,
      CN, 0, C_, ab, nullptr, nullptr, 0, C_, 1);
  // K3 [N,C] -> sA (o2T dead)
  mm_k<1, 2, 0><<<gQ, blk, 0, stream>>>(at1, CN, C_, awb + CC, 0, C_, nullptr,
      sA, CN, 0, C_, ab + C_, nullptr, nullptr, 0, C_, 1);
  // V3 [C,N] -> sC? sf still needed as... sf consumed by stats+t_cvt; V3 -> sC
  // BUT sC holds sf (bf16) which is no longer needed after t_cvt_bf above.
  mm_k<1, 1, 0><<<gV, blk, 0, stream>>>(awb + 2 * CC, 0, C_, at2, CN, C_,
      nullptr, sC, CN, 0, N_, ab + 2 * C_, nullptr, nullptr, 0, C_, 1);
  attention(sD, C_, CN, sA, C_, CN, sC, sD);  // o3T -> sD (Q3 dead after QK^T)
  // out = W3a·o3 + b3a + cf(bf16) -> d_out fp32 [C,N]
  mm_k<0, 1, 2><<<gV, blk, 0, stream>>>(awb + 3 * CC, 0, C_, sD, CN, C_, out,
      nullptr, CN, 0, N_, ab + 3 * C_, nullptr, sB, CN, C_, 1);
}